// Round 1
// baseline (424.360 us; speedup 1.0000x reference)
//
#include <hip/hip_runtime.h>
#include <math.h>

#define P 256
#define C 151
#define R 51
#define B 4
#define K (C*R)          // 7701
#define CP 160           // padded C for GEMM tiles
#define QT 64
#define KB 32
#define KSPLIT 32
#define KCHUNK ((K + KSPLIT - 1) / KSPLIT)   // 241

// ws layout (in floats)
#define OFF_M1    ((size_t)0)
#define OFF_M2    (OFF_M1 + (size_t)K*C)                 // 1,162,851
#define OFF_S1    (OFF_M2 + (size_t)K*C)
#define OFF_S2    (OFF_S1 + (size_t)B*P*K)               // 7,885,824 each
#define OFF_THETA (OFF_S2 + (size_t)B*P*K)
#define WS_FLOATS (OFF_THETA + (size_t)B*P*C)            // ~18.25M floats ~= 73 MB

// ---------------------------------------------------------------------------
// Kernel A: build M1[k][c] = w'*M[l][c][r], M2[k][c] = w'*M[c][l][r]
// (k = l*R + r, w' = 0.5*(r==0 ? 1 : 0.5)), zero theta and out.
// ---------------------------------------------------------------------------
__global__ __launch_bounds__(256) void prep_kernel(const float* __restrict__ M,
                                                   float* __restrict__ ws,
                                                   float* __restrict__ out) {
    const unsigned tid = blockIdx.x * 256u + threadIdx.x;
    if (tid == 0) *out = 0.f;
    const unsigned half = (unsigned)(K * C);
    if (tid < 2u * half) {
        unsigned t = (tid < half) ? tid : (tid - half);
        unsigned k = t / C;
        unsigned c = t - k * C;
        unsigned l = k / R;
        unsigned r = k - l * R;
        float w = (r == 0) ? 0.5f : 0.25f;
        if (tid < half) {
            ws[OFF_M1 + t] = w * M[((size_t)l * C + c) * R + r];
        } else {
            ws[OFF_M2 + t] = w * M[((size_t)c * C + l) * R + r];
        }
    }
    if (tid < (unsigned)(B * P * C)) ws[OFF_THETA + tid] = 0.f;
}

// ---------------------------------------------------------------------------
// Kernel B: one block per (n,q). Build S1[n,q,:], S2[n,q,:] in LDS, write out.
//   S1[l*R+r] = sum_{i!=q, lab_i=l} rl[n][i][q][r]
//   S2[l*R+r] = sum_{i!=q, lab_i=l} rl[n][q][i][r]
// ---------------------------------------------------------------------------
__global__ __launch_bounds__(256) void sbuild_kernel(const float* __restrict__ rel,
                                                     const int* __restrict__ labels,
                                                     float* __restrict__ ws) {
    __shared__ float s1[K];
    __shared__ float s2[K];
    __shared__ int   labs[P];   // label * R
    const int tid = threadIdx.x;
    const int bid = blockIdx.x;
    const int n = bid >> 8;
    const int q = bid & 255;

    for (int j = tid; j < K; j += 256) { s1[j] = 0.f; s2[j] = 0.f; }
    if (tid < P) labs[tid] = labels[n * P + tid] * R;
    __syncthreads();

    // S2: rl[n][q][i][r], fully contiguous P*R run
    const float* row = rel + ((size_t)(n * P + q)) * P * R;
    for (unsigned idx = tid; idx < (unsigned)(P * R); idx += 256) {
        unsigned i = idx / R;
        unsigned r = idx - i * R;
        if ((int)i != q) atomicAdd(&s2[labs[i] + r], row[idx]);
    }

    // S1: rl[n][i][q][r], stride P*R between i; wave-per-i, lanes cover r
    const int wave = tid >> 6, lane = tid & 63;
    if (lane < R) {
        const float* colbase = rel + ((size_t)n * P * P) * R + (size_t)q * R + lane;
        for (int i = wave; i < P; i += 4) {
            if (i == q) continue;
            float v = colbase[(size_t)i * P * R];
            atomicAdd(&s1[labs[i] + lane], v);
        }
    }
    __syncthreads();

    float* S1g = ws + OFF_S1 + (size_t)(n * P + q) * K;
    float* S2g = ws + OFF_S2 + (size_t)(n * P + q) * K;
    for (int j = tid; j < K; j += 256) { S1g[j] = s1[j]; S2g[j] = s2[j]; }
}

// ---------------------------------------------------------------------------
// Kernel C: theta[n,q,c] += sum_k S1[n,q,k]*M1[k,c] + S2[n,q,k]*M2[k,c]
// Tiled fp32 GEMM; 512 blocks = B(4) x qtiles(4) x KSPLIT(32); K-partials
// combined via global atomicAdd into theta.
// ---------------------------------------------------------------------------
__global__ __launch_bounds__(256) void gemm_kernel(float* __restrict__ ws) {
    __shared__ float s1t[KB][QT + 1];
    __shared__ float s2t[KB][QT + 1];
    __shared__ float m1t[KB][CP];
    __shared__ float m2t[KB][CP];

    const int tid = threadIdx.x;
    const int bid = blockIdx.x;
    const int ks = bid & (KSPLIT - 1);
    const int qt = (bid >> 5) & 3;
    const int n  = bid >> 7;
    const int q0 = qt * QT;
    const int k0 = ks * KCHUNK;
    const int kend = min(k0 + KCHUNK, K);

    const int tq   = tid >> 4;   // 0..15
    const int tsub = tid & 15;   // 0..15

    float acc[4][10];
    #pragma unroll
    for (int iq = 0; iq < 4; ++iq)
        #pragma unroll
        for (int j = 0; j < 10; ++j) acc[iq][j] = 0.f;

    const float* S1g = ws + OFF_S1 + (size_t)(n * P + q0) * K;
    const float* S2g = ws + OFF_S2 + (size_t)(n * P + q0) * K;
    const float* M1g = ws + OFF_M1;
    const float* M2g = ws + OFF_M2;

    for (int kt = k0; kt < kend; kt += KB) {
        // stage S tiles (transposed, padded to break bank conflicts)
        #pragma unroll
        for (int it = 0; it < 8; ++it) {
            int e  = tid + it * 256;       // 2048 elements
            int qq = e >> 5;
            int kk = e & (KB - 1);
            int kg = kt + kk;
            float v1 = 0.f, v2 = 0.f;
            if (kg < kend) {
                v1 = S1g[(size_t)qq * K + kg];
                v2 = S2g[(size_t)qq * K + kg];
            }
            s1t[kk][qq] = v1;
            s2t[kk][qq] = v2;
        }
        // stage M tiles (row-major, zero-padded c>=151)
        #pragma unroll
        for (int it = 0; it < 20; ++it) {
            int e  = tid + it * 256;       // 5120 elements
            int kk = e / CP;
            int c  = e - kk * CP;
            int kg = kt + kk;
            float v1 = 0.f, v2 = 0.f;
            if (kg < kend && c < C) {
                v1 = M1g[(size_t)kg * C + c];
                v2 = M2g[(size_t)kg * C + c];
            }
            m1t[kk][c] = v1;
            m2t[kk][c] = v2;
        }
        __syncthreads();

        #pragma unroll 2
        for (int kk = 0; kk < KB; ++kk) {
            float a1[4], a2[4];
            #pragma unroll
            for (int iq = 0; iq < 4; ++iq) {
                a1[iq] = s1t[kk][tq + 16 * iq];
                a2[iq] = s2t[kk][tq + 16 * iq];
            }
            #pragma unroll
            for (int j = 0; j < 10; ++j) {
                float b1 = m1t[kk][tsub + 16 * j];
                float b2 = m2t[kk][tsub + 16 * j];
                #pragma unroll
                for (int iq = 0; iq < 4; ++iq)
                    acc[iq][j] += a1[iq] * b1 + a2[iq] * b2;
            }
        }
        __syncthreads();
    }

    #pragma unroll
    for (int iq = 0; iq < 4; ++iq) {
        float* th = ws + OFF_THETA + (size_t)(n * P + q0 + tq + 16 * iq) * C;
        #pragma unroll
        for (int j = 0; j < 10; ++j) {
            int c = tsub + 16 * j;
            if (c < C) atomicAdd(&th[c], acc[iq][j]);
        }
    }
}

// ---------------------------------------------------------------------------
// Kernel D: per-row logsumexp loss; mean into out. One wave per (n,q) row.
// ---------------------------------------------------------------------------
__global__ __launch_bounds__(256) void loss_kernel(const float* __restrict__ ws,
                                                   const int* __restrict__ labels,
                                                   float* __restrict__ out) {
    const int wave = threadIdx.x >> 6, lane = threadIdx.x & 63;
    const int row = blockIdx.x * 4 + wave;          // 0..1023
    const float* th = ws + OFF_THETA + (size_t)row * C;
    float v0 = (lane < C)       ? th[lane]       : -INFINITY;
    float v1 = (lane + 64 < C)  ? th[lane + 64]  : -INFINITY;
    float v2 = (lane + 128 < C) ? th[lane + 128] : -INFINITY;
    float m = fmaxf(v0, fmaxf(v1, v2));
    #pragma unroll
    for (int o = 32; o > 0; o >>= 1) m = fmaxf(m, __shfl_xor(m, o, 64));
    float s = 0.f;
    if (lane < C)       s += expf(v0 - m);
    if (lane + 64 < C)  s += expf(v1 - m);
    if (lane + 128 < C) s += expf(v2 - m);
    #pragma unroll
    for (int o = 32; o > 0; o >>= 1) s += __shfl_xor(s, o, 64);
    if (lane == 0) {
        int lab = labels[row];
        float loss = (m + logf(s)) - th[lab];
        atomicAdd(out, loss * (1.0f / (B * P)));
    }
}

// ---------------------------------------------------------------------------
extern "C" void kernel_launch(void* const* d_in, const int* in_sizes, int n_in,
                              void* d_out, int out_size, void* d_ws, size_t ws_size,
                              hipStream_t stream) {
    // inputs: 0=roi_scores (unused), 1=rel_scores, 2=relationship_mat,
    //         3=roi_labels, 4=num_images (fixed B=4)
    const float* rel    = (const float*)d_in[1];
    const float* relmat = (const float*)d_in[2];
    const int*   labels = (const int*)d_in[3];
    float* out = (float*)d_out;
    float* ws  = (float*)d_ws;

    // A: prep M1/M2, zero theta/out
    {
        int total = 2 * K * C;
        int blocks = (total + 255) / 256;
        prep_kernel<<<blocks, 256, 0, stream>>>(relmat, ws, out);
    }
    // B: build S1/S2
    sbuild_kernel<<<B * P, 256, 0, stream>>>(rel, labels, ws);
    // C: GEMM -> theta
    gemm_kernel<<<B * 4 * KSPLIT, 256, 0, stream>>>(ws);
    // D: loss
    loss_kernel<<<B * P / 4, 256, 0, stream>>>(ws, labels, out);
}

// Round 2
// 268.785 us; speedup vs baseline: 1.5788x; 1.5788x over previous
//
#include <hip/hip_runtime.h>
#include <math.h>

#define NB 4
#define PP 256
#define CC 151
#define RR 51
#define K0 7550        // 151*50 (r=0 dropped: constant-in-c, cancels in log_softmax)
#define KP 8192        // padded K for MFMA
#define CT 160         // padded C
#define KSPLIT 32
#define CHUNK 256      // KP/KSPLIT
#define NROW 1024      // NB*PP

typedef _Float16 half8 __attribute__((ext_vector_type(8)));
typedef float floatx4 __attribute__((ext_vector_type(4)));
typedef unsigned short ushort_t;

// ws layout (bytes)
#define OFF_M1T ((size_t)0)
#define OFF_M2T ((size_t)CT*KP*2)                      // 2,621,440
#define OFF_S1  ((size_t)2*CT*KP*2)                    // 5,242,880
#define OFF_S2  (OFF_S1 + (size_t)NROW*KP*2)           // +16,777,216
#define OFF_PART (OFF_S2 + (size_t)NROW*KP*2)          // +16,777,216; part = 32*1024*160*4 = 21MB; total ~60MB

// ---------------------------------------------------------------------------
// K1: M1t[c][k]=0.25*M[l][c][r+1], M2t[c][k]=0.25*M[c][l][r+1], k=l*50+r,
// fp16, zero-padded (c>=151 or k>=7550). Also zero out.
// ---------------------------------------------------------------------------
__global__ __launch_bounds__(256) void prep_kernel(const float* __restrict__ M,
                                                   _Float16* __restrict__ m1t,
                                                   _Float16* __restrict__ m2t,
                                                   float* __restrict__ out) {
    unsigned t = blockIdx.x * 256u + threadIdx.x;
    if (t == 0) *out = 0.f;
    const unsigned half = (unsigned)CT * KP;   // 1,310,720
    unsigned e = (t >= half) ? t - half : t;
    unsigned c = e >> 13;          // / KP
    unsigned kk = e & (KP - 1);
    unsigned l = kk / 50u;
    unsigned r = kk - l * 50u;
    float v = 0.f;
    if (c < CC && kk < K0) {
        size_t src = (t < half) ? ((size_t)l * CC + c) * RR + r + 1
                                : ((size_t)c * CC + l) * RR + r + 1;
        v = 0.25f * M[src];
    }
    _Float16 h = (_Float16)v;
    if (t < half) m1t[e] = h; else m2t[e] = h;
}

// ---------------------------------------------------------------------------
// K2: per (n,q): S1[k]=sum_{i!=q,lab_i=l} rel[n,i,q,r+1], S2 same with rel[n,q,i,r+1]
// fp32 LDS accumulate -> fp16 global, zero-padded to KP.
// ---------------------------------------------------------------------------
__global__ __launch_bounds__(256) void sbuild_kernel(const float* __restrict__ rel,
                                                     const int* __restrict__ labels,
                                                     _Float16* __restrict__ S1,
                                                     _Float16* __restrict__ S2) {
    __shared__ float s1[K0 + 2];
    __shared__ float s2[K0 + 2];
    __shared__ int labs[PP];
    const int tid = threadIdx.x;
    const int n = blockIdx.x >> 8;
    const int q = blockIdx.x & 255;

    for (int j = tid; j < K0 + 2; j += 256) { s1[j] = 0.f; s2[j] = 0.f; }
    labs[tid] = labels[n * PP + tid] * 50;
    __syncthreads();

    const int wave = tid >> 6, lane = tid & 63;
    const float* rowq = rel + ((size_t)(n * PP + q)) * PP * RR;
    const float* colq = rel + (size_t)n * PP * PP * RR + (size_t)q * RR;
    if (lane >= 1 && lane < RR) {
        for (int i = wave; i < PP; i += 4) {
            if (i == q) continue;
            float v2 = rowq[(size_t)i * RR + lane];
            float v1 = colq[(size_t)i * PP * RR + lane];
            int kb = labs[i] + lane - 1;
            atomicAdd(&s2[kb], v2);
            atomicAdd(&s1[kb], v1);
        }
    }
    __syncthreads();

    _Float16* o1 = S1 + (size_t)blockIdx.x * KP;
    _Float16* o2 = S2 + (size_t)blockIdx.x * KP;
    for (int j = tid; j < KP / 4; j += 256) {
        int kk = j * 4;
        unsigned a[4], b[4];
        #pragma unroll
        for (int x = 0; x < 4; ++x) {
            float f1 = (kk + x < K0) ? s1[kk + x] : 0.f;
            float f2 = (kk + x < K0) ? s2[kk + x] : 0.f;
            union { _Float16 h; ushort_t s; } c1, c2;
            c1.h = (_Float16)f1; c2.h = (_Float16)f2;
            a[x] = c1.s; b[x] = c2.s;
        }
        uint2 u1, u2;
        u1.x = a[0] | (a[1] << 16); u1.y = a[2] | (a[3] << 16);
        u2.x = b[0] | (b[1] << 16); u2.y = b[2] | (b[3] << 16);
        ((uint2*)o1)[j] = u1;
        ((uint2*)o2)[j] = u2;
    }
}

// ---------------------------------------------------------------------------
// K3: partial[ks][row][c] = sum_{k in chunk} S1[row][k]*M1t[c][k] + S2*M2t
// 16x16x32 f16 MFMA. Block: 128 rows x 160 cols; 4 waves x (2 row-tiles x 10
// col-tiles). A-frags direct from global (fragment-aligned); B via
// global_load_lds(16B) -> LDS.
// ---------------------------------------------------------------------------
__global__ __launch_bounds__(256) void gemm_kernel(const _Float16* __restrict__ S1,
                                                   const _Float16* __restrict__ S2,
                                                   const _Float16* __restrict__ m1t,
                                                   const _Float16* __restrict__ m2t,
                                                   float* __restrict__ part) {
    __shared__ _Float16 Bt[2 * CT * 32];   // 20 KB: [mat][c][k32]
    const int tid = threadIdx.x;
    const int ks = blockIdx.x & (KSPLIT - 1);
    const int rb = blockIdx.x >> 5;        // 0..7
    const int wave = tid >> 6, lane = tid & 63;
    const int m16 = lane & 15, quad = lane >> 4;
    const int rowbase = rb * 128 + wave * 32;

    floatx4 acc[2][10];
    #pragma unroll
    for (int rt = 0; rt < 2; ++rt)
        #pragma unroll
        for (int ct = 0; ct < 10; ++ct)
            acc[rt][ct] = (floatx4){0.f, 0.f, 0.f, 0.f};

    const int k0base = ks * CHUNK;
    for (int kt = 0; kt < CHUNK; kt += 32) {
        const int k0 = k0base + kt;
        #pragma unroll
        for (int j = 0; j < 5; ++j) {
            int e = j * 256 + tid;                 // 0..1279 : 16B chunks
            int mat = (e >= CT * 4) ? 1 : 0;
            int ec = e - mat * CT * 4;
            int c = ec >> 2, qtr = ec & 3;
            const _Float16* g = (mat ? m2t : m1t) + (size_t)c * KP + k0 + qtr * 8;
            __builtin_amdgcn_global_load_lds(
                (const __attribute__((address_space(1))) unsigned int*)g,
                (__attribute__((address_space(3))) unsigned int*)(Bt + e * 8),
                16, 0, 0);
        }
        __syncthreads();
        #pragma unroll
        for (int mat = 0; mat < 2; ++mat) {
            const _Float16* Sg = mat ? S2 : S1;
            const _Float16* abase = Sg + (size_t)(rowbase + m16) * KP + k0 + quad * 8;
            half8 a0 = *(const half8*)(abase);
            half8 a1 = *(const half8*)(abase + (size_t)16 * KP);
            const _Float16* bb = Bt + (mat * CT + m16) * 32 + quad * 8;
            #pragma unroll
            for (int ct = 0; ct < 10; ++ct) {
                half8 b = *(const half8*)(bb + ct * 16 * 32);
                acc[0][ct] = __builtin_amdgcn_mfma_f32_16x16x32_f16(a0, b, acc[0][ct], 0, 0, 0);
                acc[1][ct] = __builtin_amdgcn_mfma_f32_16x16x32_f16(a1, b, acc[1][ct], 0, 0, 0);
            }
        }
        __syncthreads();
    }

    // epilogue: C/D frag row = quad*4+reg, col = m16 (m89-verified layout)
    float* pb = part + (size_t)ks * NROW * CT;
    #pragma unroll
    for (int rt = 0; rt < 2; ++rt)
        #pragma unroll
        for (int ct = 0; ct < 10; ++ct)
            #pragma unroll
            for (int reg = 0; reg < 4; ++reg) {
                int row = rowbase + rt * 16 + quad * 4 + reg;
                pb[(size_t)row * CT + ct * 16 + m16] = acc[rt][ct][reg];
            }
}

// ---------------------------------------------------------------------------
// K4: theta[row][c] = sum_ks partial; loss = lse(theta) - theta[lab]; mean.
// ---------------------------------------------------------------------------
__global__ __launch_bounds__(256) void reduce_loss_kernel(const float* __restrict__ part,
                                                          const int* __restrict__ labels,
                                                          float* __restrict__ out) {
    __shared__ float th[CT];
    const int row = blockIdx.x;
    const int t = threadIdx.x;
    if (t < CT) {
        float s = 0.f;
        #pragma unroll
        for (int ks = 0; ks < KSPLIT; ++ks)
            s += part[((size_t)ks * NROW + row) * CT + t];
        th[t] = s;
    }
    __syncthreads();
    if (t < 64) {
        float v0 = (t < CC) ? th[t] : -INFINITY;
        float v1 = (t + 64 < CC) ? th[t + 64] : -INFINITY;
        float v2 = (t + 128 < CC) ? th[t + 128] : -INFINITY;
        float m = fmaxf(v0, fmaxf(v1, v2));
        #pragma unroll
        for (int o = 32; o > 0; o >>= 1) m = fmaxf(m, __shfl_xor(m, o, 64));
        float s = 0.f;
        if (t < CC) s += expf(v0 - m);
        if (t + 64 < CC) s += expf(v1 - m);
        if (t + 128 < CC) s += expf(v2 - m);
        #pragma unroll
        for (int o = 32; o > 0; o >>= 1) s += __shfl_xor(s, o, 64);
        if (t == 0) {
            int lab = labels[row];
            atomicAdd(out, (m + logf(s) - th[lab]) * (1.0f / NROW));
        }
    }
}

// ---------------------------------------------------------------------------
extern "C" void kernel_launch(void* const* d_in, const int* in_sizes, int n_in,
                              void* d_out, int out_size, void* d_ws, size_t ws_size,
                              hipStream_t stream) {
    const float* rel    = (const float*)d_in[1];
    const float* relmat = (const float*)d_in[2];
    const int*   labels = (const int*)d_in[3];
    float* out = (float*)d_out;
    char* ws = (char*)d_ws;

    _Float16* m1t = (_Float16*)(ws + OFF_M1T);
    _Float16* m2t = (_Float16*)(ws + OFF_M2T);
    _Float16* S1  = (_Float16*)(ws + OFF_S1);
    _Float16* S2  = (_Float16*)(ws + OFF_S2);
    float*    part = (float*)(ws + OFF_PART);

    prep_kernel<<<2 * CT * KP / 256, 256, 0, stream>>>(relmat, m1t, m2t, out);
    sbuild_kernel<<<NROW, 256, 0, stream>>>(rel, labels, S1, S2);
    gemm_kernel<<<8 * KSPLIT, 256, 0, stream>>>(S1, S2, m1t, m2t, part);
    reduce_loss_kernel<<<NROW, 256, 0, stream>>>(part, labels, out);
}

// Round 3
// 208.290 us; speedup vs baseline: 2.0373x; 1.2904x over previous
//
#include <hip/hip_runtime.h>
#include <math.h>

#define NB 4
#define PP 256
#define CC 151
#define RR 51
#define CM 160             // padded C
#define KI 64              // padded per-i k stride (2 MFMA k-steps per i)
#define KT (PP*KI)         // 16384 total K
#define ML (CC*KI)         // 9664 row length of M1t/M2t
#define KS 32              // split-K factor
#define CHUNK (KT/KS)      // 512 k = 8 i's per block
#define NROW (NB*PP)       // 1024

typedef _Float16 half8 __attribute__((ext_vector_type(8)));
typedef float floatx4 __attribute__((ext_vector_type(4)));

// ws layout (bytes)
#define OFF_M1 ((size_t)0)
#define OFF_M2 (OFF_M1 + (size_t)CM*ML*2)          // +3,092,480
#define OFF_RA (OFF_M2 + (size_t)CM*ML*2)          // +3,092,480
#define OFF_RB (OFF_RA + (size_t)NROW*KT*2)        // +33,554,432
#define OFF_PT (OFF_RB + (size_t)NROW*KT*2)        // +33,554,432; part 20.97 MB; total ~94.3 MB

// ---------------------------------------------------------------------------
// K1: M1t[c][l*64+r] = w'_r * M[l][c][r], M2t[c][l*64+r] = w'_r * M[c][l][r]
// w'_0 = 0.5, w'_{r>=1} = 0.25; fp16; zero-padded r in [51,64) and c >= 151.
// ---------------------------------------------------------------------------
__global__ __launch_bounds__(256) void prep_kernel(const float* __restrict__ M,
                                                   _Float16* __restrict__ m1,
                                                   _Float16* __restrict__ m2,
                                                   float* __restrict__ out) {
    const int c = blockIdx.x;      // 0..159
    const int mat = blockIdx.y;    // 0,1
    if (c == 0 && mat == 0 && threadIdx.x == 0) *out = 0.f;
    _Float16* dst = (mat ? m2 : m1) + (size_t)c * ML;
    for (int e = threadIdx.x; e < ML; e += 256) {
        int l = e >> 6, r = e & 63;
        float v = 0.f;
        if (r < RR && c < CC) {
            size_t src = ((size_t)(mat ? c * CC + l : l * CC + c)) * RR + r;
            v = (r == 0 ? 0.5f : 0.25f) * M[src];
        }
        dst[e] = (_Float16)v;
    }
}

// ---------------------------------------------------------------------------
// K2: cast/transpose. relAt[n][q][i*64+r] = rel[n][i][q][r] (diag i==q -> 0)
//     relBt[n][q][i*64+r] = rel[n][q][i][r] (diag -> 0), r>=51 -> 0.
// One block per (n, a-tile16, b-tile16). Reads coalesced; relBt written
// straight from load regs; relAt via LDS tile transpose. No atomics.
// ---------------------------------------------------------------------------
__global__ __launch_bounds__(256) void transp_kernel(const float* __restrict__ rel,
                                                     _Float16* __restrict__ ra,
                                                     _Float16* __restrict__ rb) {
    __shared__ _Float16 lds[16 * 1024];   // [b_local][a_local*64+r], 32 KB
    const int bid = blockIdx.x;
    const int n  = bid >> 8;
    const int a0 = ((bid >> 4) & 15) << 4;
    const int b0 = (bid & 15) << 4;
    const float* relbase = rel + (size_t)n * PP * PP * RR;

    for (int e2 = threadIdx.x; e2 < 8192; e2 += 256) {
        int e = e2 * 2;                 // pairs of r slots
        int a = e >> 10, j = e & 1023;  // j = b_local*64 + r
        int bl = j >> 6, r = j & 63;
        int ga = a0 + a, gb = b0 + bl;
        float v0 = 0.f, v1 = 0.f;
        if (ga != gb) {
            const float* src = relbase + ((size_t)ga * PP + gb) * RR;
            if (r < RR)     v0 = src[r];
            if (r + 1 < RR) v1 = src[r + 1];
        }
        union { _Float16 h[2]; unsigned u; } pk;
        pk.h[0] = (_Float16)v0; pk.h[1] = (_Float16)v1;
        *(unsigned*)(&lds[(size_t)bl * 1024 + a * 64 + r]) = pk.u;
        *(unsigned*)(&rb[((size_t)(n * PP + ga)) * KT + b0 * 64 + j]) = pk.u;
    }
    __syncthreads();
    for (int e2 = threadIdx.x; e2 < 8192; e2 += 256) {
        int e = e2 * 2;
        int bl = e >> 10, j = e & 1023;     // j = a_local*64 + r
        *(unsigned*)(&ra[((size_t)(n * PP + b0 + bl)) * KT + a0 * 64 + j]) =
            *(const unsigned*)(&lds[e]);
    }
}

// ---------------------------------------------------------------------------
// K3: partial[ks][row][c] = sum_{k chunk} relAt[row][k]*M1t[c][k-gathered]
//                                       + relBt[row][k]*M2t[c][k-gathered]
// B-tiles gathered per-i by label straight from M1t/M2t (L2-resident) via
// global_load_lds(16B). 16x16x32 f16 MFMA. Grid 512 = 4 img x 4 rowblk x 32 ks.
// ---------------------------------------------------------------------------
__global__ __launch_bounds__(256) void gemm_kernel(const _Float16* __restrict__ ra,
                                                   const _Float16* __restrict__ rb,
                                                   const _Float16* __restrict__ m1,
                                                   const _Float16* __restrict__ m2,
                                                   const int* __restrict__ labels,
                                                   float* __restrict__ part) {
    __shared__ _Float16 Bt[2 * CM * 32];   // 20,480 B: chunks [mat][qtr][c] of 8 halves
    __shared__ int labs[CHUNK / KI];       // 8 labels
    const int tid = threadIdx.x;
    const int ks  = blockIdx.x & 31;
    const int rbk = (blockIdx.x >> 5) & 3;
    const int n   = blockIdx.x >> 7;
    const int wave = tid >> 6, lane = tid & 63;
    const int m16 = lane & 15, quad = lane >> 4;
    const int kc0 = ks * CHUNK;
    const int rowg = n * PP + rbk * 64 + wave * 16;   // wave's 16-row base

    if (tid < CHUNK / KI) labs[tid] = labels[n * PP + (kc0 >> 6) + tid];
    __syncthreads();

    floatx4 acc[10];
    #pragma unroll
    for (int ct = 0; ct < 10; ++ct) acc[ct] = (floatx4){0.f, 0.f, 0.f, 0.f};

    for (int h = 0; h < CHUNK / 32; ++h) {           // 16 k-steps
        const int k0 = kc0 + h * 32;
        const int lab = labs[h >> 1];
        const int moff = lab * KI + (h & 1) * 32;    // within one i
        #pragma unroll
        for (int j = 0; j < 5; ++j) {
            int s = j * 256 + tid;                   // 0..1279 16B chunks
            int mat = (s >= 640) ? 1 : 0;
            int t2 = s - mat * 640;
            int qtr = t2 / 160;                      // k-offset/8 within step
            int c   = t2 - qtr * 160;
            const _Float16* g = (mat ? m2 : m1) + (size_t)c * ML + moff + qtr * 8;
            __builtin_amdgcn_global_load_lds(
                (const __attribute__((address_space(1))) unsigned int*)g,
                (__attribute__((address_space(3))) unsigned int*)(Bt + (size_t)s * 8),
                16, 0, 0);
        }
        __syncthreads();
        #pragma unroll
        for (int mat = 0; mat < 2; ++mat) {
            const _Float16* A = mat ? rb : ra;
            half8 a = *(const half8*)(A + (size_t)(rowg + m16) * KT + k0 + quad * 8);
            const _Float16* bb = Bt + ((size_t)(mat * 4 + quad) * 160 + m16) * 8;
            #pragma unroll
            for (int ct = 0; ct < 10; ++ct) {
                half8 b = *(const half8*)(bb + ct * 128);
                acc[ct] = __builtin_amdgcn_mfma_f32_16x16x32_f16(a, b, acc[ct], 0, 0, 0);
            }
        }
        __syncthreads();
    }

    // C/D layout: row = quad*4+reg, col = ct*16+m16 (m89-verified)
    #pragma unroll
    for (int ct = 0; ct < 10; ++ct)
        #pragma unroll
        for (int reg = 0; reg < 4; ++reg) {
            int row = rowg + quad * 4 + reg;
            part[((size_t)ks * NROW + row) * CM + ct * 16 + m16] = acc[ct][reg];
        }
}

// ---------------------------------------------------------------------------
// K4: theta[row][c] = sum_ks partial; loss = lse(theta) - theta[lab]; mean.
// ---------------------------------------------------------------------------
__global__ __launch_bounds__(256) void reduce_loss_kernel(const float* __restrict__ part,
                                                          const int* __restrict__ labels,
                                                          float* __restrict__ out) {
    __shared__ float th[CM];
    const int row = blockIdx.x;
    const int t = threadIdx.x;
    if (t < CM) {
        float s = 0.f;
        #pragma unroll
        for (int ks = 0; ks < KS; ++ks)
            s += part[((size_t)ks * NROW + row) * CM + t];
        th[t] = s;
    }
    __syncthreads();
    if (t < 64) {
        float v0 = (t < CC)       ? th[t]       : -INFINITY;
        float v1 = (t + 64 < CC)  ? th[t + 64]  : -INFINITY;
        float v2 = (t + 128 < CC) ? th[t + 128] : -INFINITY;
        float m = fmaxf(v0, fmaxf(v1, v2));
        #pragma unroll
        for (int o = 32; o > 0; o >>= 1) m = fmaxf(m, __shfl_xor(m, o, 64));
        float s = 0.f;
        if (t < CC)       s += expf(v0 - m);
        if (t + 64 < CC)  s += expf(v1 - m);
        if (t + 128 < CC) s += expf(v2 - m);
        #pragma unroll
        for (int o = 32; o > 0; o >>= 1) s += __shfl_xor(s, o, 64);
        if (t == 0) {
            atomicAdd(out, (m + logf(s) - th[labels[row]]) * (1.0f / NROW));
        }
    }
}

// ---------------------------------------------------------------------------
extern "C" void kernel_launch(void* const* d_in, const int* in_sizes, int n_in,
                              void* d_out, int out_size, void* d_ws, size_t ws_size,
                              hipStream_t stream) {
    // inputs: 0=roi_scores (unused), 1=rel_scores, 2=relationship_mat,
    //         3=roi_labels, 4=num_images (fixed B=4)
    const float* rel    = (const float*)d_in[1];
    const float* relmat = (const float*)d_in[2];
    const int*   labels = (const int*)d_in[3];
    float* out = (float*)d_out;
    char* ws = (char*)d_ws;

    _Float16* m1 = (_Float16*)(ws + OFF_M1);
    _Float16* m2 = (_Float16*)(ws + OFF_M2);
    _Float16* ra = (_Float16*)(ws + OFF_RA);
    _Float16* rb = (_Float16*)(ws + OFF_RB);
    float*  part = (float*)(ws + OFF_PT);

    prep_kernel<<<dim3(CM, 2), 256, 0, stream>>>(relmat, m1, m2, out);
    transp_kernel<<<NB * 256, 256, 0, stream>>>(rel, ra, rb);
    gemm_kernel<<<NB * 4 * KS, 256, 0, stream>>>(ra, rb, m1, m2, labels, part);
    reduce_loss_kernel<<<NROW, 256, 0, stream>>>(part, labels, out);
}

// Round 4
// 183.721 us; speedup vs baseline: 2.3098x; 1.1337x over previous
//
#include <hip/hip_runtime.h>
#include <math.h>

#define NB 4
#define PP 256
#define CC 151
#define RR 51
#define CM 160                 // padded C
#define KI 64                  // padded per-i k slots (r 51..63 zero in M)
#define ML (CC*KI)             // 9664 halves per c-row of M1/M2
#define KS 64                  // split-K: 4 i's per block
#define NROW (NB*PP)           // 1024
#define RELTOT (NB*PP*PP*RR)   // 13,369,344 floats
#define ALIM (RELTOT - 8)

typedef _Float16 half8 __attribute__((ext_vector_type(8)));
typedef float floatx4 __attribute__((ext_vector_type(4)));

// ws layout (bytes): m1, m2, part
#define OFF_M1 ((size_t)0)
#define OFF_M2 (OFF_M1 + (size_t)CM*ML*2)      // +3,092,480
#define OFF_PT (OFF_M2 + (size_t)CM*ML*2)      // +3,092,480; part 41.9 MB; total ~48 MB

// ---------------------------------------------------------------------------
// K1: M1[c][l*64+r] = w_r*M[l][c][r], M2[c][l*64+r] = w_r*M[c][l][r]
// w_0 = 0.5, w_{r>=1} = 0.25; fp16; zero pad r in [51,64) and c >= 151.
// ---------------------------------------------------------------------------
__global__ __launch_bounds__(256) void prep_kernel(const float* __restrict__ M,
                                                   _Float16* __restrict__ m1,
                                                   _Float16* __restrict__ m2,
                                                   float* __restrict__ out) {
    const int c = blockIdx.x;      // 0..159
    const int mat = blockIdx.y;    // 0,1
    if (c == 0 && mat == 0 && threadIdx.x == 0) *out = 0.f;
    _Float16* dst = (mat ? m2 : m1) + (size_t)c * ML;
    for (int e = threadIdx.x; e < ML; e += 256) {
        int l = e >> 6, r = e & 63;
        float v = 0.f;
        if (r < RR && c < CC) {
            size_t src = ((size_t)(mat ? c * CC + l : l * CC + c)) * RR + r;
            v = (r == 0 ? 0.5f : 0.25f) * M[src];
        }
        dst[e] = (_Float16)v;
    }
}

// ---------------------------------------------------------------------------
// K2 (fused transpose+GEMM):
// part[ks][row q][c] = sum_{i in chunk, r} rel[n,i,q,r]*w_r*M[lab_i,c,r]
//                                        + rel[n,q,i,r]*w_r*M[c,lab_i,r]
// A read straight from rel (fp32 dwords, cvt in reg; pad slots hit B zeros,
// diagonal zeroed by select, tail load clamped). B gathered per-(i,mat,half)
// from L2-resident M1/M2 via global_load_lds, double-buffered LDS.
// Grid 1024 = 4 img x 4 rowblk x 64 ks. 16 mat-steps of k=32 per block.
// ---------------------------------------------------------------------------
__global__ __launch_bounds__(256) void gemm_kernel(const float* __restrict__ rel,
                                                   const _Float16* __restrict__ m1,
                                                   const _Float16* __restrict__ m2,
                                                   const int* __restrict__ labels,
                                                   float* __restrict__ part) {
    __shared__ _Float16 Bt[2][640 * 8];    // 2 x 10 KB double buffer
    const int tid  = threadIdx.x;
    const int ks   = blockIdx.x & 63;
    const int rbk  = (blockIdx.x >> 6) & 3;
    const int n    = blockIdx.x >> 8;
    const int wave = tid >> 6, lane = tid & 63;
    const int m16  = lane & 15, quad = lane >> 4;
    const int i0   = ks * 4;
    const int qimg = rbk * 64 + wave * 16 + m16;    // this lane's A row (in-image)

    int labs[4];
    #pragma unroll
    for (int j = 0; j < 4; ++j) labs[j] = labels[n * PP + i0 + j];

    floatx4 acc[10];
    #pragma unroll
    for (int ct = 0; ct < 10; ++ct) acc[ct] = (floatx4){0.f, 0.f, 0.f, 0.f};

    // stage B tile for step h into buffer buf: 640 chunks of 16B,
    // chunk s = oct*160 + c ; lane-contiguous dest (wave-uniform base + lane*16)
    auto stageB = [&](int h, int buf) {
        const int ii = h >> 2, mh = (h >> 1) & 1, half = h & 1;
        const _Float16* base = mh ? m2 : m1;
        const int lab = labs[ii];
        #pragma unroll
        for (int j = 0; j < 3; ++j) {
            int s = j * 256 + tid;
            if (s < 640) {
                int oct = s / 160;
                int c = s - oct * 160;
                const _Float16* g = base + (size_t)c * ML + lab * KI + half * 32 + oct * 8;
                __builtin_amdgcn_global_load_lds(
                    (const __attribute__((address_space(1))) unsigned int*)g,
                    (__attribute__((address_space(3))) unsigned int*)(&Bt[buf][(size_t)s * 8]),
                    16, 0, 0);
            }
        }
    };
    // load this lane's 8 fp32 A elements for step h (clamped, unmasked)
    auto loadA = [&](int h, float* v) {
        const int ii = h >> 2, mh = (h >> 1) & 1, half = h & 1;
        const int i = i0 + ii;
        int idx = mh ? ((n * PP + qimg) * PP + i) * RR + half * 32 + quad * 8
                     : ((n * PP + i) * PP + qimg) * RR + half * 32 + quad * 8;
        idx = min(idx, ALIM);
        const float* p = rel + idx;
        #pragma unroll
        for (int j = 0; j < 8; ++j) v[j] = p[j];
    };

    stageB(0, 0);
    float av[8];
    loadA(0, av);

    #pragma unroll
    for (int h = 0; h < 16; ++h) {
        __syncthreads();                       // B(h) + av now resident
        if (h < 15) stageB(h + 1, (h + 1) & 1);
        float avn[8];
        if (h < 15) loadA(h + 1, avn);

        const bool dz = (i0 + (h >> 2)) == qimg;   // diagonal i == q
        half8 a;
        #pragma unroll
        for (int j = 0; j < 8; ++j) a[j] = (_Float16)(dz ? 0.f : av[j]);

        const _Float16* bb = &Bt[h & 1][((size_t)quad * 160 + m16) * 8];
        #pragma unroll
        for (int ct = 0; ct < 10; ++ct) {
            half8 b = *(const half8*)(bb + ct * 128);
            acc[ct] = __builtin_amdgcn_mfma_f32_16x16x32_f16(a, b, acc[ct], 0, 0, 0);
        }
        #pragma unroll
        for (int j = 0; j < 8; ++j) av[j] = avn[j];
    }

    // C/D layout: col = m16, row = quad*4+reg (m89-verified)
    float* pb = part + ((size_t)ks * NROW + n * PP + rbk * 64 + wave * 16) * CM;
    #pragma unroll
    for (int ct = 0; ct < 10; ++ct)
        #pragma unroll
        for (int reg = 0; reg < 4; ++reg)
            pb[(size_t)(quad * 4 + reg) * CM + ct * 16 + m16] = acc[ct][reg];
}

// ---------------------------------------------------------------------------
// K3: theta[row][c] = sum_ks part; loss = lse(theta) - theta[lab]; mean.
// ---------------------------------------------------------------------------
__global__ __launch_bounds__(256) void reduce_loss_kernel(const float* __restrict__ part,
                                                          const int* __restrict__ labels,
                                                          float* __restrict__ out) {
    __shared__ float th[CM];
    const int row = blockIdx.x;
    const int t = threadIdx.x;
    if (t < CM) {
        float s = 0.f;
        #pragma unroll
        for (int ks = 0; ks < KS; ++ks)
            s += part[((size_t)ks * NROW + row) * CM + t];
        th[t] = s;
    }
    __syncthreads();
    if (t < 64) {
        float v0 = (t < CC)       ? th[t]       : -INFINITY;
        float v1 = (t + 64 < CC)  ? th[t + 64]  : -INFINITY;
        float v2 = (t + 128 < CC) ? th[t + 128] : -INFINITY;
        float m = fmaxf(v0, fmaxf(v1, v2));
        #pragma unroll
        for (int o = 32; o > 0; o >>= 1) m = fmaxf(m, __shfl_xor(m, o, 64));
        float s = 0.f;
        if (t < CC)       s += expf(v0 - m);
        if (t + 64 < CC)  s += expf(v1 - m);
        if (t + 128 < CC) s += expf(v2 - m);
        #pragma unroll
        for (int o = 32; o > 0; o >>= 1) s += __shfl_xor(s, o, 64);
        if (t == 0) {
            atomicAdd(out, (m + logf(s) - th[labels[row]]) * (1.0f / NROW));
        }
    }
}

// ---------------------------------------------------------------------------
extern "C" void kernel_launch(void* const* d_in, const int* in_sizes, int n_in,
                              void* d_out, int out_size, void* d_ws, size_t ws_size,
                              hipStream_t stream) {
    // inputs: 0=roi_scores (unused), 1=rel_scores, 2=relationship_mat,
    //         3=roi_labels, 4=num_images (fixed B=4)
    const float* rel    = (const float*)d_in[1];
    const float* relmat = (const float*)d_in[2];
    const int*   labels = (const int*)d_in[3];
    float* out = (float*)d_out;
    char* ws = (char*)d_ws;

    _Float16* m1 = (_Float16*)(ws + OFF_M1);
    _Float16* m2 = (_Float16*)(ws + OFF_M2);
    float*  part = (float*)(ws + OFF_PT);

    prep_kernel<<<dim3(CM, 2), 256, 0, stream>>>(relmat, m1, m2, out);
    gemm_kernel<<<NB * 4 * KS, 256, 0, stream>>>(rel, m1, m2, labels, part);
    reduce_loss_kernel<<<NROW, 256, 0, stream>>>(part, labels, out);
}

// Round 5
// 165.969 us; speedup vs baseline: 2.5569x; 1.1070x over previous
//
#include <hip/hip_runtime.h>
#include <math.h>

#define NB 4
#define PP 256
#define CC 151
#define RR 51
#define CM 160                 // padded C (5 tiles of 32)
#define KI 64                  // padded per-i k slots (r in [51,64) zero in M)
#define KS 64                  // split-K: 4 i's per block
#define NROW (NB*PP)           // 1024
#define RELTOT (NB*PP*PP*RR)   // 13,369,344 floats
#define ALIM (RELTOT - 8)
#define MLB 10240              // halves per l in m-layout: 8 oct * 160 c * 8 j

typedef _Float16 half8 __attribute__((ext_vector_type(8)));
typedef float floatx16 __attribute__((ext_vector_type(16)));

// ws layout (bytes): m1g, m2g, part
#define OFF_M1 ((size_t)0)
#define OFF_M2 (OFF_M1 + (size_t)CC*MLB*2)     // +3,092,480
#define OFF_PT (OFF_M2 + (size_t)CC*MLB*2)     // part: 64*1024*160*4 = 41.9 MB

// ---------------------------------------------------------------------------
// K1: streaming-friendly M layout.
// m1g[l][oct][c][j] = w_r * M[l][c][oct*8+j]   (r = oct*8+j)
// m2g[l][oct][c][j] = w_r * M[c][l][oct*8+j]
// w_0 = 0.5, w_{r>=1} = 0.25; zero for r >= 51 or c >= 151.
// A k16-step's B-tile (2 octs x 160 c x 8 j) is 5 KB CONTIGUOUS.
// ---------------------------------------------------------------------------
__global__ __launch_bounds__(256) void prep_kernel(const float* __restrict__ M,
                                                   _Float16* __restrict__ m1,
                                                   _Float16* __restrict__ m2,
                                                   float* __restrict__ out) {
    const int l = blockIdx.x;      // 0..150
    const int mat = blockIdx.y;    // 0,1
    if (l == 0 && mat == 0 && threadIdx.x == 0) *out = 0.f;
    _Float16* dst = (mat ? m2 : m1) + (size_t)l * MLB;
    for (int e = threadIdx.x; e < MLB; e += 256) {
        int oct = e / 1280;
        int rem = e - oct * 1280;
        int c = rem >> 3, j = rem & 7;
        int r = oct * 8 + j;
        float v = 0.f;
        if (r < RR && c < CC) {
            size_t src = ((size_t)(mat ? c * CC + l : l * CC + c)) * RR + r;
            v = (r == 0 ? 0.5f : 0.25f) * M[src];
        }
        dst[e] = (_Float16)v;
    }
}

// ---------------------------------------------------------------------------
// K2 (fused transpose+GEMM, 32x32x16 MFMA):
// part[ks][row q][c] = sum_{i in chunk, r} rel[n,i,q,r]*w_r*M[lab_i,c,r]
//                                        + rel[n,q,i,r]*w_r*M[c,lab_i,r]
// Block: 128 rows x 160 c; 4 waves x (32 rows x 5 c-tiles). 32 steps of k=16
// (4 i x 2 mat x 4 k-steps). B staged as one contiguous 5 KB global_load_lds
// burst per step (double-buffered); A direct fp32->reg, cvt, diag zeroed.
// Grid 512 = 4 img x 2 rowblk x 64 ks.
// ---------------------------------------------------------------------------
__global__ __launch_bounds__(256) void gemm_kernel(const float* __restrict__ rel,
                                                   const _Float16* __restrict__ m1,
                                                   const _Float16* __restrict__ m2,
                                                   const int* __restrict__ labels,
                                                   float* __restrict__ part) {
    __shared__ _Float16 Bt[2][2560];       // 2 x 5 KB
    const int tid  = threadIdx.x;
    const int ks   = blockIdx.x & 63;
    const int rbk  = (blockIdx.x >> 6) & 1;
    const int n    = blockIdx.x >> 7;
    const int wave = tid >> 6, lane = tid & 63;
    const int m32  = lane & 31, kh = lane >> 5;
    const int i0   = ks * 4;
    const int rowimg = rbk * 128 + wave * 32 + m32;   // this lane's A row (q, in-image)

    int labs[4];
    #pragma unroll
    for (int j = 0; j < 4; ++j) labs[j] = labels[n * PP + i0 + j];

    floatx16 acc[5];
    #pragma unroll
    for (int ct = 0; ct < 5; ++ct)
        #pragma unroll
        for (int r2 = 0; r2 < 16; ++r2) acc[ct][r2] = 0.f;

    // step h = (i_loc<<3) | (mat<<2) | t ; t = k16-step within the 64 slots
    auto stageB = [&](int h, int buf) {
        const int il = h >> 3, mh = (h >> 2) & 1, t = h & 3;
        const _Float16* base = (mh ? m2 : m1) + (size_t)labs[il] * MLB + t * 2560;
        #pragma unroll
        for (int j = 0; j < 2; ++j) {
            int s = j * 256 + tid;               // 320 chunks of 16B, contiguous
            if (s < 320) {
                __builtin_amdgcn_global_load_lds(
                    (const __attribute__((address_space(1))) unsigned int*)(base + s * 8),
                    (__attribute__((address_space(3))) unsigned int*)(&Bt[buf][(size_t)s * 8]),
                    16, 0, 0);
            }
        }
    };
    auto loadA = [&](int h, float* v) {
        const int il = h >> 3, mh = (h >> 2) & 1, t = h & 3;
        const int i = i0 + il;
        const int r0 = t * 16 + kh * 8;
        int idx = mh ? ((n * PP + rowimg) * PP + i) * RR + r0
                     : ((n * PP + i) * PP + rowimg) * RR + r0;
        idx = min(idx, ALIM);     // only reachable on the i==q==255 diagonal (zeroed)
        const float* p = rel + idx;
        #pragma unroll
        for (int j = 0; j < 8; ++j) v[j] = p[j];
    };

    stageB(0, 0);
    float av[8];
    loadA(0, av);

    #pragma unroll 2
    for (int h = 0; h < 32; ++h) {
        __syncthreads();                       // B(h) staged, av(h) in regs
        if (h < 31) stageB(h + 1, (h + 1) & 1);
        float avn[8];
        if (h < 31) loadA(h + 1, avn);

        const bool dz = (i0 + (h >> 3)) == rowimg;   // diagonal i == q
        half8 a;
        #pragma unroll
        for (int j = 0; j < 8; ++j) a[j] = (_Float16)(dz ? 0.f : av[j]);

        // B-frag: n = m32 (+ct*32), k = kh*8+j -> chunk (kh*160 + ct*32 + m32)
        const _Float16* bb = &Bt[h & 1][(size_t)(kh * 160 + m32) * 8];
        #pragma unroll
        for (int ct = 0; ct < 5; ++ct) {
            half8 b = *(const half8*)(bb + ct * 256);
            acc[ct] = __builtin_amdgcn_mfma_f32_32x32x16_f16(a, b, acc[ct], 0, 0, 0);
        }
        #pragma unroll
        for (int j = 0; j < 8; ++j) av[j] = avn[j];
    }

    // C/D 32x32 layout (m74/m101): col = m32, row = (reg&3) + 8*(reg>>2) + 4*kh
    float* pb = part + ((size_t)ks * NROW + n * PP + rbk * 128 + wave * 32) * CM;
    #pragma unroll
    for (int ct = 0; ct < 5; ++ct)
        #pragma unroll
        for (int reg = 0; reg < 16; ++reg) {
            int row = (reg & 3) + 8 * (reg >> 2) + 4 * kh;
            pb[(size_t)row * CM + ct * 32 + m32] = acc[ct][reg];
        }
}

// ---------------------------------------------------------------------------
// K3: theta[row][c] = sum_ks part; loss = lse(theta) - theta[lab]; mean.
// ---------------------------------------------------------------------------
__global__ __launch_bounds__(256) void reduce_loss_kernel(const float* __restrict__ part,
                                                          const int* __restrict__ labels,
                                                          float* __restrict__ out) {
    __shared__ float th[CM];
    const int row = blockIdx.x;
    const int t = threadIdx.x;
    if (t < CM) {
        float s = 0.f;
        #pragma unroll
        for (int ks = 0; ks < KS; ++ks)
            s += part[((size_t)ks * NROW + row) * CM + t];
        th[t] = s;
    }
    __syncthreads();
    if (t < 64) {
        float v0 = (t < CC)       ? th[t]       : -INFINITY;
        float v1 = (t + 64 < CC)  ? th[t + 64]  : -INFINITY;
        float v2 = (t + 128 < CC) ? th[t + 128] : -INFINITY;
        float m = fmaxf(v0, fmaxf(v1, v2));
        #pragma unroll
        for (int o = 32; o > 0; o >>= 1) m = fmaxf(m, __shfl_xor(m, o, 64));
        float s = 0.f;
        if (t < CC)       s += expf(v0 - m);
        if (t + 64 < CC)  s += expf(v1 - m);
        if (t + 128 < CC) s += expf(v2 - m);
        #pragma unroll
        for (int o = 32; o > 0; o >>= 1) s += __shfl_xor(s, o, 64);
        if (t == 0) {
            atomicAdd(out, (m + logf(s) - th[labels[row]]) * (1.0f / NROW));
        }
    }
}

// ---------------------------------------------------------------------------
extern "C" void kernel_launch(void* const* d_in, const int* in_sizes, int n_in,
                              void* d_out, int out_size, void* d_ws, size_t ws_size,
                              hipStream_t stream) {
    // inputs: 0=roi_scores (unused), 1=rel_scores, 2=relationship_mat,
    //         3=roi_labels, 4=num_images (fixed B=4)
    const float* rel    = (const float*)d_in[1];
    const float* relmat = (const float*)d_in[2];
    const int*   labels = (const int*)d_in[3];
    float* out = (float*)d_out;
    char* ws = (char*)d_ws;

    _Float16* m1 = (_Float16*)(ws + OFF_M1);
    _Float16* m2 = (_Float16*)(ws + OFF_M2);
    float*  part = (float*)(ws + OFF_PT);

    prep_kernel<<<dim3(CC, 2), 256, 0, stream>>>(relmat, m1, m2, out);
    gemm_kernel<<<NB * 2 * KS, 256, 0, stream>>>(rel, m1, m2, labels, part);
    reduce_loss_kernel<<<NROW, 256, 0, stream>>>(part, labels, out);
}